// Round 15
// baseline (111.330 us; speedup 1.0000x reference)
//
#include <hip/hip_runtime.h>

// Problem constants (fixed by setup_inputs)
#define BATCH 2
#define NPTS  8192
#define KS    16
#define KNN   8
#define R2LOOSE 0.0101f      // loose prefilter ball; exact radius test at end
#define KEYMASK 0xFFFFE000u  // high 19 bits of d2; low 13 bits = sorted pos
#define NCELL   1000         // 10x10x10 grid, cell size 0.1 (= RADIUS)
#define CSTRIDE 1024         // padded per-batch cell-array stride

// Kernel geometry
#define QB       64                 // queries per block (= wave size)
#define NWAVE    8                  // waves per block (512 threads)
#define NTHREADS 512
#define CAP      32                 // collect capacity per thread
#define TILEC    1024               // candidates staged per LDS tile
#define NBLK     (BATCH * NPTS / QB)   // 256 blocks = CU count (co-resident)
#define FLAG_DONE 0xAAAAAABAu       // 0xAAAAAAAA poison + 16 builder blocks

__device__ __forceinline__ int cell_of(float x, float y, float z) {
    int cx = (int)(x * 10.0f); cx = cx > 9 ? 9 : cx;
    int cy = (int)(y * 10.0f); cy = cy > 9 ? 9 : cy;
    int cz = (int)(z * 10.0f); cz = cz > 9 ? 9 : cz;
    return (cx * 10 + cy) * 10 + cz;
}

// ---- single fused kernel: build (blocks 0..15) -> flag -> knn+loss ---------
__global__ __launch_bounds__(512) void knn_fused_kernel(
    const float* __restrict__ pc,    // (B, N, 3)
    const float* __restrict__ mask,  // (B, N, KS)
    float4* __restrict__ cs,         // ws: cell-sorted (x,y,z,-0.5|c|^2)
    int*    __restrict__ sidx,       // ws: sorted pos -> orig idx
    int*    __restrict__ cstart,     // ws: per-batch cell starts (padded 1024)
    unsigned* __restrict__ flag,     // ws: poison 0xAAAAAAAA; +1 per builder
    float*  __restrict__ out)        // scalar
{
    __shared__ float4   tile[TILEC];           // 16 KB staged candidates
    __shared__ int      tsp[TILEC];            //  4 KB their sorted positions
    __shared__ unsigned sbuf[CAP * NTHREADS];  // 64 KB (build aliases h here)
    __shared__ int      fidx[QB * KNN];        //  2 KB
    __shared__ int      qid[QB];
    __shared__ float    red[NWAVE];

    const int t   = threadIdx.x;
    const int blk = blockIdx.x;
    const int lane = t & 63, w = t >> 6;

    // ============ phase 1: grid build (builder blocks 0..15 only) ===========
    // block = batch*8 + segment. Private LDS histogram built in barrier-
    // enforced segment order: during its OWN segment's adds, atomicAdd's
    // return value = (count in earlier segments) + intra-segment rank =
    // the scatter cursor (R14-verified trick, reshaped to 512 threads).
    if (blk < 16) {
        int* h  = (int*)sbuf;          // 1024 cell counts -> cell starts
        int* w8 = (int*)sbuf + 1024;   // 8 wave partial sums
        const int b = blk >> 3, seg = blk & 7;
        h[t] = 0; h[t + 512] = 0;
        if (blk == 0 && t == 0) out[0] = 0.0f;   // published via fence chain

        const float* p = pc + (size_t)b * NPTS * 3;
        float X[16], Y[16], Z[16]; int CC[16];   // 8 segments x 2 points
#pragma unroll
        for (int j = 0; j < 8; ++j) {
#pragma unroll
            for (int k = 0; k < 2; ++k) {
                const int i = j * 1024 + k * 512 + t;
                X[2*j+k] = p[3*i]; Y[2*j+k] = p[3*i+1]; Z[2*j+k] = p[3*i+2];
                CC[2*j+k] = cell_of(X[2*j+k], Y[2*j+k], Z[2*j+k]);
            }
        }
        __syncthreads();   // h zeroed

        int my0 = 0, my1 = 0;
#pragma unroll
        for (int j = 0; j < 8; ++j) {            // segment-ordered adds
            const int o0 = atomicAdd(&h[CC[2*j]],   1);
            const int o1 = atomicAdd(&h[CC[2*j+1]], 1);
            if (j == seg) { my0 = o0; my1 = o1; }
            __syncthreads();
        }

        // exclusive scan of 1024 cell totals with 512 threads (cell pairs)
        const int a0 = h[2*t], a1 = h[2*t+1];
        const int psum = a0 + a1;
        int inc = psum;
#pragma unroll
        for (int off = 1; off < 64; off <<= 1) {
            const int v = __shfl_up(inc, off);
            if (lane >= off) inc += v;
        }
        if (lane == 63) w8[w] = inc;
        __syncthreads();
        if (w == 0) {
            const int v = (lane < 8) ? w8[lane] : 0;
            int iv = v;
#pragma unroll
            for (int off = 1; off < 8; off <<= 1) {
                const int u = __shfl_up(iv, off);
                if (lane >= off) iv += u;
            }
            if (lane < 8) w8[lane] = iv - v;     // exclusive wave offsets
        }
        __syncthreads();
        const int excl = inc - psum + w8[w];     // pair-exclusive prefix
        const int c0 = excl, c1 = excl + a0;     // per-cell starts
        if (seg == 0) {
            cstart[b * CSTRIDE + 2*t]     = c0;  // cells >= NCELL -> 8192
            cstart[b * CSTRIDE + 2*t + 1] = c1;
        }
        __syncthreads();
        h[2*t] = c0; h[2*t+1] = c1;
        __syncthreads();

        // select own-segment points (compile-time j, uniform seg -> no scratch)
        float x0=X[0], y0=Y[0], z0=Z[0]; int cc0=CC[0];
        float x1=X[1], y1=Y[1], z1=Z[1]; int cc1=CC[1];
#pragma unroll
        for (int j = 1; j < 8; ++j)
            if (seg == j) {
                x0=X[2*j]; y0=Y[2*j]; z0=Z[2*j]; cc0=CC[2*j];
                x1=X[2*j+1]; y1=Y[2*j+1]; z1=Z[2*j+1]; cc1=CC[2*j+1];
            }
        {
            const int pos = h[cc0] + my0;
            const float sq = fmaf(z0, z0, fmaf(y0, y0, x0 * x0));
            cs[b * NPTS + pos]   = make_float4(x0, y0, z0, -0.5f * sq);
            sidx[b * NPTS + pos] = seg * 1024 + t;
        }
        {
            const int pos = h[cc1] + my1;
            const float sq = fmaf(z1, z1, fmaf(y1, y1, x1 * x1));
            cs[b * NPTS + pos]   = make_float4(x1, y1, z1, -0.5f * sq);
            sidx[b * NPTS + pos] = seg * 1024 + 512 + t;
        }
        __threadfence();        // device-scope release of cs/sidx/cstart/out
        __syncthreads();
        if (t == 0) atomicAdd(flag, 1u);
    }

    // ============ flag gate: all 256 blocks co-resident, spin is safe =======
    while (__hip_atomic_load(flag, __ATOMIC_RELAXED,
                             __HIP_MEMORY_SCOPE_AGENT) != FLAG_DONE)
        __builtin_amdgcn_s_sleep(8);
    __threadfence();            // device-scope acquire: build now visible
    __syncthreads();            // builders: LDS reuse (sbuf) safe after this

    // ============ phase 2: fused knn + loss (R14-identical) =================
    const int q  = t & (QB - 1);  // query slot (lane)
    const int s  = t >> 6;        // wave id 0..7
    const int su = __builtin_amdgcn_readfirstlane(s);
    const int b  = blk >> 7;
    const int q0 = (blk & 127) * QB;      // sorted-position base
    const int qpos = q0 + q;

    const float4* csb = cs + b * NPTS;
    const float4 qc = csb[qpos];
    const int    qi = sidx[b * NPTS + qpos];
    if (s == 0) qid[q] = qi;

    const float qx = qc.x, qy = qc.y, qz = qc.z;
    const float qs = -2.0f * qc.w;                 // exact (power of 2)
    const float negthr = (qs - R2LOOSE) * 0.5f;    // pass iff tt >= negthr
    const unsigned SENT = (__float_as_uint(R2LOOSE) & KEYMASK) | 0x1FFFu;

    // block's contiguous lex-cell run
    int lex = cell_of(qx, qy, qz);
    int cmn = lex, cmx = lex;
#pragma unroll
    for (int off = 32; off; off >>= 1) {
        cmn = min(cmn, __shfl_xor(cmn, off));
        cmx = max(cmx, __shfl_xor(cmx, off));
    }
    const int cfirst = __builtin_amdgcn_readfirstlane(cmn);
    const int clast  = __builtin_amdgcn_readfirstlane(cmx);

    // Three covering lex intervals (named scalars; dedup clamps; wrapped
    // spurious cells fail the prefilter -- R5..R14-verified).
    int lo0 = cfirst - 111, h0 = clast - 89;
    int lo1 = cfirst - 11,  h1 = clast + 11;
    int lo2 = cfirst + 89,  h2 = clast + 111;
    lo0 = min(max(lo0, 0), 1000);
    lo1 = min(max(lo1, 0), 1000);
    lo2 = min(max(lo2, 0), 1000);
    int hp0 = min(max(h0 + 1, 0), 1000);
    int hp1 = min(max(h1 + 1, 0), 1000);
    int hp2 = min(max(h2 + 1, 0), 1000);
    lo1 = max(lo1, hp0);   // dedup guards (no-ops in the typical case)
    lo2 = max(lo2, hp1);

    const int* csp = cstart + b * CSTRIDE;
    const int P0 = csp[lo0], E0 = csp[hp0];
    const int P1 = csp[lo1], E1 = csp[hp1];
    const int P2 = csp[lo2], E2 = csp[hp2];
    const int L0 = max(0, E0 - P0);
    const int L1 = max(0, E1 - P1);
    const int L2 = max(0, E2 - P2);
    const int C  = L0 + L1 + L2;        // total candidates (typ. ~760)

    // append-only collect, branchless: always store, advance cursor on pass.
    int cnt = 0;
    auto EVAL = [&](const float4& c, int spos) {
        const float tt = fmaf(c.x, qx, fmaf(c.y, qy, fmaf(c.z, qz, c.w)));
        const float d2 = fmaxf(fmaf(-2.0f, tt, qs), 0.0f);
        const unsigned key =
            (__float_as_uint(d2) & KEYMASK) | (unsigned)spos;
        const int slot = cnt < (CAP - 1) ? cnt : (CAP - 1);
        sbuf[slot * NTHREADS + t] = key;
        cnt += (tt >= negthr) ? 1 : 0;
    };

    // Tiled collect: cooperative wide staging into LDS, then wave-uniform
    // broadcast scan from LDS.
    for (int tb = 0; tb < C; tb += TILEC) {
        const int nt = min(TILEC, C - tb);
        for (int p = t; p < nt; p += NTHREADS) {    // <= 2 iters, 512-wide
            const int g = tb + p;
            int sp = P0 + g;                         // flat -> sorted pos
            sp = (g >= L0)      ? (P1 + (g - L0))      : sp;
            sp = (g >= L0 + L1) ? (P2 + (g - L0 - L1)) : sp;
            tile[p] = csb[sp];                       // coalesced 16 B/lane
            tsp[p]  = sp;
        }
        __syncthreads();

        int j = (su * nt) >> 3;                      // wave's uniform slice
        const int e = ((su + 1) * nt) >> 3;
        for (; j + 4 <= e; j += 4) {
            const float4 c0 = tile[j],     c1 = tile[j + 1];
            const float4 c2 = tile[j + 2], c3 = tile[j + 3];
            const int s0 = tsp[j],     s1 = tsp[j + 1];
            const int s2 = tsp[j + 2], s3 = tsp[j + 3];
            EVAL(c0, s0); EVAL(c1, s1); EVAL(c2, s2); EVAL(c3, s3);
        }
        for (; j < e; ++j) { const float4 c0 = tile[j]; EVAL(c0, tsp[j]); }
        __syncthreads();
    }

    // per-thread sort of collected keys into top-8 (own column, no barrier)
    unsigned md[KNN];
#pragma unroll
    for (int k = 0; k < KNN; ++k) md[k] = SENT;
    const int m = cnt < CAP ? cnt : CAP;
    for (int k = 0; k < m; ++k) {
        unsigned ky = sbuf[k * NTHREADS + t];
#pragma unroll
        for (int i = 0; i < KNN; ++i) {
            const unsigned mn = min(ky, md[i]);
            const unsigned mx = max(ky, md[i]);
            md[i] = mn; ky = mx;
        }
    }
    __syncthreads();   // collect reads done before row-relayout

    {   // publish sorted top-8 (row layout)
        uint4* bp = (uint4*)&sbuf[t * KNN];
        bp[0] = make_uint4(md[0], md[1], md[2], md[3]);
        bp[1] = make_uint4(md[4], md[5], md[6], md[7]);
    }
    __syncthreads();

    // wave 0: single-stage merge, exact radius test, emit orig-index fidx
    if (s == 0) {
        for (int l = 1; l < NWAVE; ++l) {
            const uint4* lp = (const uint4*)&sbuf[(l * QB + q) * KNN];
            const uint4 r0 = lp[0], r1 = lp[1];
            const unsigned tk[8] = {r0.x, r0.y, r0.z, r0.w,
                                    r1.x, r1.y, r1.z, r1.w};
#pragma unroll
            for (int k = 0; k < 8; ++k) {
                unsigned ky = tk[k];
                if (ky < md[KNN - 1]) {    // sentinel skip
#pragma unroll
                    for (int i = 0; i < KNN; ++i) {
                        const unsigned mn = min(ky, md[i]);
                        const unsigned mx = max(ky, md[i]);
                        md[i] = mn; ky = mx;
                    }
                }
            }
        }
#pragma unroll
        for (int k = 0; k < KNN; ++k) {
            const unsigned ky = md[k];
            int nb;
            if (ky >= SENT) {
                nb = qi;  // unfilled -> self (contributes 0, matches ref)
            } else {
                const int sp = (int)(ky & 0x1FFFu);
                const float4 cc = csb[sp];
                const float dx = cc.x - qx;
                const float dy = cc.y - qy;
                const float dz = cc.z - qz;
                const float d2 = fmaf(dx, dx, fmaf(dy, dy, dz * dz));
                // reference: idx = where(sqrt(d2) > 0.1, self_idx, idx)
                nb = (sqrtf(d2) > 0.1f) ? qi : sidx[b * NPTS + sp];
            }
            fidx[q * KNN + k] = nb;
        }
    }
    __syncthreads();

    // loss gather: 512 threads <-> 64 q x 8 nn, full 16-ch rows
    const int q2 = t >> 3;
    const int j2 = t & 7;
    const int qg = qid[q2];
    const int nb = fidx[q2 * KNN + j2];
    const float* mrow = mask + ((size_t)b * NPTS + qg) * KS;
    const float* nrow = mask + ((size_t)b * NPTS + nb) * KS;
    float acc = 0.0f;
#pragma unroll
    for (int c2 = 0; c2 < KS; c2 += 4) {
        const float4 a = *(const float4*)(mrow + c2);
        const float4 v = *(const float4*)(nrow + c2);
        acc += fabsf(a.x - v.x) + fabsf(a.y - v.y) +
               fabsf(a.z - v.z) + fabsf(a.w - v.w);
    }

    // block reduction: wave shuffle -> LDS -> one atomic per block
#pragma unroll
    for (int off = 32; off > 0; off >>= 1) acc += __shfl_down(acc, off);
    if ((t & 63) == 0) red[s] = acc;
    __syncthreads();
    if (t == 0) {
        float sum = 0.0f;
#pragma unroll
        for (int i = 0; i < NWAVE; ++i) sum += red[i];
        atomicAdd(out, sum * (1.0f / (BATCH * NPTS * KNN)));
    }
}

extern "C" void kernel_launch(void* const* d_in, const int* in_sizes, int n_in,
                              void* d_out, int out_size, void* d_ws, size_t ws_size,
                              hipStream_t stream) {
    const float* pc   = (const float*)d_in[0];  // (2, 8192, 3)
    const float* mask = (const float*)d_in[1];  // (2, 8192, 16)
    float* out = (float*)d_out;                 // scalar, poisoned 0xAA each call

    // workspace layout (~336 KB used); flag relies on 0xAA poison each call
    float4*   cs     = (float4*)d_ws;                            // 256 KB
    int*      sidx   = (int*)((char*)d_ws + 262144);             //  64 KB
    int*      cstart = (int*)((char*)d_ws + 327680);             //   8 KB
    unsigned* flag   = (unsigned*)((char*)d_ws + 335872);        //   4 B

    hipLaunchKernelGGL(knn_fused_kernel, dim3(NBLK), dim3(NTHREADS), 0, stream,
                       pc, mask, cs, sidx, cstart, flag, out);
}

// Round 16
// 79.683 us; speedup vs baseline: 1.3972x; 1.3972x over previous
//
#include <hip/hip_runtime.h>

// Problem constants (fixed by setup_inputs)
#define BATCH 2
#define NPTS  8192
#define KS    16
#define KNN   8
#define R2LOOSE 0.0101f      // loose prefilter ball; exact radius test at end
#define KEYMASK 0xFFFFE000u  // high 19 bits of d2; low 13 bits = sorted pos
#define NCELL   1000         // 10x10x10 grid, cell size 0.1 (= RADIUS)
#define CSTRIDE 1024         // padded per-batch cell-array stride

// Main kernel geometry: 512 blocks (2/CU co-resident), 32 queries/block
#define QB       32                 // queries per block
#define NSLICE   16                 // candidate slices (half-wave each)
#define NTHREADS 512
#define NWAVE    8
#define CAP      24                 // collect capacity per thread
#define TILEC    512                // candidates staged per LDS tile
#define NBLK     (BATCH * NPTS / QB)   // 512 blocks

__device__ __forceinline__ int cell_of(float x, float y, float z) {
    int cx = (int)(x * 10.0f); cx = cx > 9 ? 9 : cx;
    int cy = (int)(y * 10.0f); cy = cy > 9 ? 9 : cy;
    int cz = (int)(z * 10.0f); cz = cz > 9 ? 9 : cz;
    return (cx * 10 + cy) * 10 + cz;
}

// ---- single build node (R14-verified): histogram + scan + scatter ----------
__global__ __launch_bounds__(1024) void build_kernel(
    const float* __restrict__ pc,
    float4* __restrict__ cs, int* __restrict__ sidx,
    int* __restrict__ cstart, float* __restrict__ out)
{
    __shared__ int h[1024];
    __shared__ int wsum[16];
    const int blk = blockIdx.x, t = threadIdx.x;
    const int b = blk >> 3, seg = blk & 7;     // batch, own segment
    const int lane = t & 63, w = t >> 6;

    h[t] = 0;
    if (blk == 0 && t == 0) out[0] = 0.0f;     // runs before main in-stream

    const float* p = pc + (size_t)b * NPTS * 3;
    float X[8], Y[8], Z[8]; int CC[8];
#pragma unroll
    for (int j = 0; j < 8; ++j) {
        const int i = j * 1024 + t;
        X[j] = p[3 * i]; Y[j] = p[3 * i + 1]; Z[j] = p[3 * i + 2];
        CC[j] = cell_of(X[j], Y[j], Z[j]);
    }
    __syncthreads();   // h zeroed

    int myold = 0;
#pragma unroll
    for (int j = 0; j < 8; ++j) {              // segment-ordered adds
        const int old = atomicAdd(&h[CC[j]], 1);
        if (j == seg) myold = old;             // bel + intra-seg rank
        __syncthreads();
    }

    const int sum = h[t];
    int inc = sum;
#pragma unroll
    for (int off = 1; off < 64; off <<= 1) {
        const int v = __shfl_up(inc, off);
        if (lane >= off) inc += v;
    }
    if (lane == 63) wsum[w] = inc;
    __syncthreads();
    if (w == 0) {
        const int v = (lane < 16) ? wsum[lane] : 0;
        int iv = v;
#pragma unroll
        for (int off = 1; off < 16; off <<= 1) {
            const int u = __shfl_up(iv, off);
            if (lane >= off) iv += u;
        }
        if (lane < 16) wsum[lane] = iv - v;    // exclusive wave offsets
    }
    __syncthreads();
    const int excl = inc - sum + wsum[w];      // per-batch exclusive prefix
    if (seg == 0) cstart[b * CSTRIDE + t] = excl;   // cells>=1000 -> 8192
    __syncthreads();
    h[t] = excl;
    __syncthreads();

    float mx = X[0], my_ = Y[0], mz = Z[0]; int mc = CC[0];
#pragma unroll
    for (int j = 1; j < 8; ++j)
        if (seg == j) { mx = X[j]; my_ = Y[j]; mz = Z[j]; mc = CC[j]; }

    const int pos = h[mc] + myold;
    const float sq = fmaf(mz, mz, fmaf(my_, my_, mx * mx));
    cs[b * NPTS + pos]   = make_float4(mx, my_, mz, -0.5f * sq);
    sidx[b * NPTS + pos] = seg * 1024 + t;     // orig within-batch index
}

// ---- fused knn + loss: 512 blocks, 2/CU, 32 queries/block ------------------
__global__ __launch_bounds__(512, 4) void knn_loss_kernel(
    const float4* __restrict__ cs,     // cell-sorted (x,y,z,-0.5|c|^2)
    const int*    __restrict__ sidx,   // sorted pos -> orig idx
    const int*    __restrict__ cstart, // per-batch cell starts (padded 1024)
    const float*  __restrict__ mask,   // (B, N, KS) in ORIGINAL order
    float* __restrict__ out)
{
    __shared__ float4   tile[TILEC];           // 8 KB staged candidates
    __shared__ int      tsp[TILEC];            // 2 KB their sorted positions
    __shared__ unsigned sbuf[CAP * NTHREADS];  // 48 KB collect/merge buffer
    __shared__ int      fidx[QB * KNN];        // 1 KB final neighbor idx
    __shared__ int      qid[QB];
    __shared__ float    red[NWAVE];
    // total ~60 KB -> 2 blocks/CU co-resident (inter-block latency overlap)

    const int t = threadIdx.x;
    const int q = t & (QB - 1);   // query slot 0..31 (lanes i and i+32 share q)
    const int s = t >> 5;         // slice id 0..15 (half-wave granularity)
    const int blk = blockIdx.x;
    const int b  = blk >> 8;
    const int q0 = (blk & 255) * QB;      // sorted-position base
    const int qpos = q0 + q;

    const float4* csb = cs + b * NPTS;
    const float4 qc = csb[qpos];
    const int    qi = sidx[b * NPTS + qpos];
    if (t < QB) qid[q] = qi;

    const float qx = qc.x, qy = qc.y, qz = qc.z;
    const float qs = -2.0f * qc.w;                 // exact (power of 2)
    const float negthr = (qs - R2LOOSE) * 0.5f;    // pass iff tt >= negthr
    const unsigned SENT = (__float_as_uint(R2LOOSE) & KEYMASK) | 0x1FFFu;

    // block's contiguous lex-cell run (lanes i, i+32 duplicate queries, so a
    // full-wave reduce is still correct; all waves compute identically)
    int lex = cell_of(qx, qy, qz);
    int cmn = lex, cmx = lex;
#pragma unroll
    for (int off = 32; off; off >>= 1) {
        cmn = min(cmn, __shfl_xor(cmn, off));
        cmx = max(cmx, __shfl_xor(cmx, off));
    }
    const int cfirst = __builtin_amdgcn_readfirstlane(cmn);
    const int clast  = __builtin_amdgcn_readfirstlane(cmx);

    // Three covering lex intervals (named scalars; dedup clamps; wrapped
    // spurious cells fail the prefilter -- R5..R14-verified, generic in run).
    int lo0 = cfirst - 111, h0 = clast - 89;
    int lo1 = cfirst - 11,  h1 = clast + 11;
    int lo2 = cfirst + 89,  h2 = clast + 111;
    lo0 = min(max(lo0, 0), 1000);
    lo1 = min(max(lo1, 0), 1000);
    lo2 = min(max(lo2, 0), 1000);
    int hp0 = min(max(h0 + 1, 0), 1000);
    int hp1 = min(max(h1 + 1, 0), 1000);
    int hp2 = min(max(h2 + 1, 0), 1000);
    lo1 = max(lo1, hp0);   // dedup guards (no-ops in the typical case)
    lo2 = max(lo2, hp1);

    const int* csp = cstart + b * CSTRIDE;
    const int P0 = csp[lo0], E0 = csp[hp0];
    const int P1 = csp[lo1], E1 = csp[hp1];
    const int P2 = csp[lo2], E2 = csp[hp2];
    const int L0 = max(0, E0 - P0);
    const int L1 = max(0, E1 - P1);
    const int L2 = max(0, E2 - P2);
    const int C  = L0 + L1 + L2;        // total candidates (typ. ~700)

    // append-only collect, branchless: always store, advance cursor on pass.
    int cnt = 0;
    auto EVAL = [&](const float4& c, int spos) {
        const float tt = fmaf(c.x, qx, fmaf(c.y, qy, fmaf(c.z, qz, c.w)));
        const float d2 = fmaxf(fmaf(-2.0f, tt, qs), 0.0f);
        const unsigned key =
            (__float_as_uint(d2) & KEYMASK) | (unsigned)spos;
        const int slot = cnt < (CAP - 1) ? cnt : (CAP - 1);
        sbuf[slot * NTHREADS + t] = key;
        cnt += (tt >= negthr) ? 1 : 0;
    };

    // Tiled collect: cooperative wide staging into LDS, then per-slice scan
    // (half-wave slices -> 2-address ds_read per wave: 2-way, conflict-free).
    for (int tb = 0; tb < C; tb += TILEC) {
        const int nt = min(TILEC, C - tb);
        if (t < nt) {                                // 1 cand/thread, 512-wide
            const int g = tb + t;
            int sp = P0 + g;                         // flat -> sorted pos
            sp = (g >= L0)      ? (P1 + (g - L0))      : sp;
            sp = (g >= L0 + L1) ? (P2 + (g - L0 - L1)) : sp;
            tile[t] = csb[sp];                       // coalesced 16 B/lane
            tsp[t]  = sp;
        }
        __syncthreads();

        int j = (s * nt) >> 4;                       // slice's sub-range
        const int e = ((s + 1) * nt) >> 4;
        for (; j + 4 <= e; j += 4) {
            const float4 c0 = tile[j],     c1 = tile[j + 1];
            const float4 c2 = tile[j + 2], c3 = tile[j + 3];
            const int s0 = tsp[j],     s1 = tsp[j + 1];
            const int s2 = tsp[j + 2], s3 = tsp[j + 3];
            EVAL(c0, s0); EVAL(c1, s1); EVAL(c2, s2); EVAL(c3, s3);
        }
        for (; j < e; ++j) { const float4 c0 = tile[j]; EVAL(c0, tsp[j]); }
        __syncthreads();
    }

    // per-thread sort of collected keys into top-8 (own column, no barrier)
    unsigned md[KNN];
#pragma unroll
    for (int k = 0; k < KNN; ++k) md[k] = SENT;
    const int m = cnt < CAP ? cnt : CAP;
    for (int k = 0; k < m; ++k) {
        unsigned ky = sbuf[k * NTHREADS + t];
#pragma unroll
        for (int i = 0; i < KNN; ++i) {
            const unsigned mn = min(ky, md[i]);
            const unsigned mx = max(ky, md[i]);
            md[i] = mn; ky = mx;
        }
    }
    __syncthreads();   // collect reads done before row-relayout

    {   // publish sorted top-8 (row layout, t = s*QB + q)
        uint4* bp = (uint4*)&sbuf[t * KNN];
        bp[0] = make_uint4(md[0], md[1], md[2], md[3]);
        bp[1] = make_uint4(md[4], md[5], md[6], md[7]);
    }
    __syncthreads();

    // threads 0..31 (= slice 0, own md is list 0): merge lists 1..15,
    // exact radius test, emit orig-index fidx
    if (t < QB) {
        for (int l = 1; l < NSLICE; ++l) {
            const uint4* lp = (const uint4*)&sbuf[(l * QB + q) * KNN];
            const uint4 r0 = lp[0], r1 = lp[1];
            const unsigned tk[8] = {r0.x, r0.y, r0.z, r0.w,
                                    r1.x, r1.y, r1.z, r1.w};
#pragma unroll
            for (int k = 0; k < 8; ++k) {
                unsigned ky = tk[k];
                if (ky < md[KNN - 1]) {    // sentinel skip
#pragma unroll
                    for (int i = 0; i < KNN; ++i) {
                        const unsigned mn = min(ky, md[i]);
                        const unsigned mx = max(ky, md[i]);
                        md[i] = mn; ky = mx;
                    }
                }
            }
        }
#pragma unroll
        for (int k = 0; k < KNN; ++k) {
            const unsigned ky = md[k];
            int nb;
            if (ky >= SENT) {
                nb = qi;  // unfilled -> self (contributes 0, matches ref)
            } else {
                const int sp = (int)(ky & 0x1FFFu);
                const float4 cc = csb[sp];
                const float dx = cc.x - qx;
                const float dy = cc.y - qy;
                const float dz = cc.z - qz;
                const float d2 = fmaf(dx, dx, fmaf(dy, dy, dz * dz));
                // reference: idx = where(sqrt(d2) > 0.1, self_idx, idx)
                nb = (sqrtf(d2) > 0.1f) ? qi : sidx[b * NPTS + sp];
            }
            fidx[q * KNN + k] = nb;
        }
    }
    __syncthreads();

    // loss gather: 512 threads <-> 32 q x 8 nn x 2 half-rows
    const int q2 = t >> 4;
    const int j2 = (t >> 1) & 7;
    const int h  = t & 1;
    const int qg = qid[q2];
    const int nb = fidx[q2 * KNN + j2];
    const float* mrow = mask + ((size_t)b * NPTS + qg) * KS + h * 8;
    const float* nrow = mask + ((size_t)b * NPTS + nb) * KS + h * 8;
    float acc = 0.0f;
#pragma unroll
    for (int c = 0; c < 8; c += 4) {
        const float4 a = *(const float4*)(mrow + c);
        const float4 v = *(const float4*)(nrow + c);
        acc += fabsf(a.x - v.x) + fabsf(a.y - v.y) +
               fabsf(a.z - v.z) + fabsf(a.w - v.w);
    }

    // block reduction: wave shuffle -> LDS -> one atomic per block
#pragma unroll
    for (int off = 32; off > 0; off >>= 1) acc += __shfl_down(acc, off);
    if ((t & 63) == 0) red[t >> 6] = acc;
    __syncthreads();
    if (t == 0) {
        float sum = 0.0f;
#pragma unroll
        for (int i = 0; i < NWAVE; ++i) sum += red[i];
        atomicAdd(out, sum * (1.0f / (BATCH * NPTS * KNN)));
    }
}

extern "C" void kernel_launch(void* const* d_in, const int* in_sizes, int n_in,
                              void* d_out, int out_size, void* d_ws, size_t ws_size,
                              hipStream_t stream) {
    const float* pc   = (const float*)d_in[0];  // (2, 8192, 3)
    const float* mask = (const float*)d_in[1];  // (2, 8192, 16)
    float* out = (float*)d_out;                 // scalar, poisoned 0xAA each call

    // workspace layout (336 KB used)
    float4* cs     = (float4*)d_ws;                              // 256 KB
    int*    sidx   = (int*)((char*)d_ws + 262144);               //  64 KB
    int*    cstart = (int*)((char*)d_ws + 327680);               //   8 KB

    hipLaunchKernelGGL(build_kernel, dim3(16), dim3(1024), 0, stream,
                       pc, cs, sidx, cstart, out);
    hipLaunchKernelGGL(knn_loss_kernel, dim3(NBLK), dim3(NTHREADS), 0, stream,
                       cs, sidx, cstart, mask, out);
}

// Round 17
// 77.193 us; speedup vs baseline: 1.4422x; 1.0323x over previous
//
#include <hip/hip_runtime.h>

// Problem constants (fixed by setup_inputs)
#define BATCH 2
#define NPTS  8192
#define KS    16
#define KNN   8
#define R2LOOSE 0.0101f      // loose prefilter ball; exact radius test at end
#define KEYMASK 0xFFFFE000u  // high 19 bits of d2; low 13 bits = sorted pos
#define NCELL   1000         // 10x10x10 grid, cell size 0.1 (= RADIUS)
#define CSTRIDE 1024         // padded per-batch cell-array stride

// Main kernel geometry
#define QB       64                 // queries per block (= wave size)
#define NWAVE    8                  // waves per block (512 threads)
#define NTHREADS 512
#define CAP      32                 // collect capacity per thread
#define TILEC    1024               // candidates staged per LDS tile
#define NBLK     (BATCH * NPTS / QB)   // 256 blocks

__device__ __forceinline__ int cell_of(float x, float y, float z) {
    int cx = (int)(x * 10.0f); cx = cx > 9 ? 9 : cx;
    int cy = (int)(y * 10.0f); cy = cy > 9 ? 9 : cy;
    int cz = (int)(z * 10.0f); cz = cz > 9 ? 9 : cz;
    return (cx * 10 + cy) * 10 + cz;
}

// ---- single build node: redundant per-block histogram + scan + scatter -----
// 16 blocks x 1024 threads; block = batch*8 + segment. Each block adds its
// batch's 8 segments to a private LDS histogram in barrier-enforced segment
// order; during its OWN segment's add, atomicAdd's return value is exactly
// (count in earlier segments) + (intra-segment rank) = the scatter cursor.
__global__ __launch_bounds__(1024) void build_kernel(
    const float* __restrict__ pc,
    float4* __restrict__ cs, int* __restrict__ sidx,
    int* __restrict__ cstart, float* __restrict__ out)
{
    __shared__ int h[1024];
    __shared__ int wsum[16];
    const int blk = blockIdx.x, t = threadIdx.x;
    const int b = blk >> 3, seg = blk & 7;     // batch, own segment
    const int lane = t & 63, w = t >> 6;

    h[t] = 0;
    if (blk == 0 && t == 0) out[0] = 0.0f;     // runs before main in-stream

    // preload one point per segment (8 points per thread, coalesced)
    const float* p = pc + (size_t)b * NPTS * 3;
    float X[8], Y[8], Z[8]; int CC[8];
#pragma unroll
    for (int j = 0; j < 8; ++j) {
        const int i = j * 1024 + t;
        X[j] = p[3 * i]; Y[j] = p[3 * i + 1]; Z[j] = p[3 * i + 2];
        CC[j] = cell_of(X[j], Y[j], Z[j]);
    }
    __syncthreads();   // h zeroed, all loads issued

    int myold = 0;
#pragma unroll
    for (int j = 0; j < 8; ++j) {              // segment-ordered adds
        const int old = atomicAdd(&h[CC[j]], 1);
        if (j == seg) myold = old;             // bel + intra-seg rank
        __syncthreads();
    }

    // wave-structured exclusive scan of the 1024 cell totals
    const int sum = h[t];
    int inc = sum;
#pragma unroll
    for (int off = 1; off < 64; off <<= 1) {
        const int v = __shfl_up(inc, off);
        if (lane >= off) inc += v;
    }
    if (lane == 63) wsum[w] = inc;
    __syncthreads();
    if (w == 0) {
        const int v = (lane < 16) ? wsum[lane] : 0;
        int iv = v;
#pragma unroll
        for (int off = 1; off < 16; off <<= 1) {
            const int u = __shfl_up(iv, off);
            if (lane >= off) iv += u;
        }
        if (lane < 16) wsum[lane] = iv - v;    // exclusive wave offsets
    }
    __syncthreads();
    const int excl = inc - sum + wsum[w];      // per-batch exclusive prefix
    if (seg == 0) cstart[b * CSTRIDE + t] = excl;   // cells>=1000 -> 8192
    __syncthreads();
    h[t] = excl;                               // per-cell start, reusable
    __syncthreads();

    // select own-segment point (uniform seg -> cndmask chain, no scratch)
    float mx = X[0], my_ = Y[0], mz = Z[0]; int mc = CC[0];
#pragma unroll
    for (int j = 1; j < 8; ++j)
        if (seg == j) { mx = X[j]; my_ = Y[j]; mz = Z[j]; mc = CC[j]; }

    const int pos = h[mc] + myold;
    const float sq = fmaf(mz, mz, fmaf(my_, my_, mx * mx));
    cs[b * NPTS + pos]   = make_float4(mx, my_, mz, -0.5f * sq);
    sidx[b * NPTS + pos] = seg * 1024 + t;     // orig within-batch index
}

// ---- fused knn + loss (R12/R14 best-measured kernel) -----------------------
__global__ __launch_bounds__(512) void knn_loss_kernel(
    const float4* __restrict__ cs,     // cell-sorted (x,y,z,-0.5|c|^2)
    const int*    __restrict__ sidx,   // sorted pos -> orig idx
    const int*    __restrict__ cstart, // per-batch cell starts (padded 1024)
    const float*  __restrict__ mask,   // (B, N, KS) in ORIGINAL order
    float* __restrict__ out)
{
    __shared__ float4   tile[TILEC];           // 16 KB staged candidates
    __shared__ int      tsp[TILEC];            //  4 KB their sorted positions
    __shared__ unsigned sbuf[CAP * NTHREADS];  // 64 KB collect/merge buffer
    __shared__ int      fidx[QB * KNN];        //  2 KB
    __shared__ int      qid[QB];
    __shared__ float    red[NWAVE];

    const int t = threadIdx.x;
    const int q = t & (QB - 1);   // query slot (lane)
    const int s = t >> 6;         // wave id 0..7
    const int su = __builtin_amdgcn_readfirstlane(s);  // wave-uniform wave id
    const int blk = blockIdx.x;
    const int b  = blk >> 7;
    const int q0 = (blk & 127) * QB;      // sorted-position base
    const int qpos = q0 + q;

    const float4* csb = cs + b * NPTS;
    const float4 qc = csb[qpos];
    const int    qi = sidx[b * NPTS + qpos];
    if (s == 0) qid[q] = qi;

    const float qx = qc.x, qy = qc.y, qz = qc.z;
    const float qs = -2.0f * qc.w;                 // exact (power of 2)
    const float negthr = (qs - R2LOOSE) * 0.5f;    // pass iff tt >= negthr
    const unsigned SENT = (__float_as_uint(R2LOOSE) & KEYMASK) | 0x1FFFu;

    // block's contiguous lex-cell run (all waves compute identically)
    int lex = cell_of(qx, qy, qz);
    int cmn = lex, cmx = lex;
#pragma unroll
    for (int off = 32; off; off >>= 1) {
        cmn = min(cmn, __shfl_xor(cmn, off));
        cmx = max(cmx, __shfl_xor(cmx, off));
    }
    const int cfirst = __builtin_amdgcn_readfirstlane(cmn);
    const int clast  = __builtin_amdgcn_readfirstlane(cmx);

    // Three covering lex intervals (named scalars; dedup clamps; wrapped
    // spurious cells fail the prefilter -- R5..R14-verified).
    int lo0 = cfirst - 111, h0 = clast - 89;
    int lo1 = cfirst - 11,  h1 = clast + 11;
    int lo2 = cfirst + 89,  h2 = clast + 111;
    lo0 = min(max(lo0, 0), 1000);
    lo1 = min(max(lo1, 0), 1000);
    lo2 = min(max(lo2, 0), 1000);
    int hp0 = min(max(h0 + 1, 0), 1000);
    int hp1 = min(max(h1 + 1, 0), 1000);
    int hp2 = min(max(h2 + 1, 0), 1000);
    lo1 = max(lo1, hp0);   // dedup guards (no-ops in the typical case)
    lo2 = max(lo2, hp1);

    const int* csp = cstart + b * CSTRIDE;
    const int P0 = csp[lo0], E0 = csp[hp0];
    const int P1 = csp[lo1], E1 = csp[hp1];
    const int P2 = csp[lo2], E2 = csp[hp2];
    const int L0 = max(0, E0 - P0);
    const int L1 = max(0, E1 - P1);
    const int L2 = max(0, E2 - P2);
    const int C  = L0 + L1 + L2;        // total candidates (typ. ~760)

    // append-only collect, branchless: always store, advance cursor on pass.
    int cnt = 0;
    auto EVAL = [&](const float4& c, int spos) {
        const float tt = fmaf(c.x, qx, fmaf(c.y, qy, fmaf(c.z, qz, c.w)));
        const float d2 = fmaxf(fmaf(-2.0f, tt, qs), 0.0f);
        const unsigned key =
            (__float_as_uint(d2) & KEYMASK) | (unsigned)spos;
        const int slot = cnt < (CAP - 1) ? cnt : (CAP - 1);
        sbuf[slot * NTHREADS + t] = key;
        cnt += (tt >= negthr) ? 1 : 0;
    };

    // Tiled collect: cooperative wide staging into LDS, then wave-uniform
    // broadcast scan from LDS.
    for (int tb = 0; tb < C; tb += TILEC) {
        const int nt = min(TILEC, C - tb);
        for (int p = t; p < nt; p += NTHREADS) {    // <= 2 iters, 512-wide
            const int g = tb + p;
            int sp = P0 + g;                         // flat -> sorted pos
            sp = (g >= L0)      ? (P1 + (g - L0))      : sp;
            sp = (g >= L0 + L1) ? (P2 + (g - L0 - L1)) : sp;
            tile[p] = csb[sp];                       // coalesced 16 B/lane
            tsp[p]  = sp;
        }
        __syncthreads();

        int j = (su * nt) >> 3;                      // wave's uniform slice
        const int e = ((su + 1) * nt) >> 3;
        for (; j + 4 <= e; j += 4) {
            const float4 c0 = tile[j],     c1 = tile[j + 1];
            const float4 c2 = tile[j + 2], c3 = tile[j + 3];
            const int s0 = tsp[j],     s1 = tsp[j + 1];
            const int s2 = tsp[j + 2], s3 = tsp[j + 3];
            EVAL(c0, s0); EVAL(c1, s1); EVAL(c2, s2); EVAL(c3, s3);
        }
        for (; j < e; ++j) { const float4 c0 = tile[j]; EVAL(c0, tsp[j]); }
        __syncthreads();
    }

    // per-thread sort of collected keys into top-8 (own column, no barrier)
    unsigned md[KNN];
#pragma unroll
    for (int k = 0; k < KNN; ++k) md[k] = SENT;
    const int m = cnt < CAP ? cnt : CAP;
    for (int k = 0; k < m; ++k) {
        unsigned ky = sbuf[k * NTHREADS + t];
#pragma unroll
        for (int i = 0; i < KNN; ++i) {
            const unsigned mn = min(ky, md[i]);
            const unsigned mx = max(ky, md[i]);
            md[i] = mn; ky = mx;
        }
    }
    __syncthreads();   // collect reads done before row-relayout

    {   // publish sorted top-8 (row layout)
        uint4* bp = (uint4*)&sbuf[t * KNN];
        bp[0] = make_uint4(md[0], md[1], md[2], md[3]);
        bp[1] = make_uint4(md[4], md[5], md[6], md[7]);
    }
    __syncthreads();

    // wave 0: single-stage merge, exact radius test, emit orig-index fidx
    if (s == 0) {
        for (int l = 1; l < NWAVE; ++l) {
            const uint4* lp = (const uint4*)&sbuf[(l * QB + q) * KNN];
            const uint4 r0 = lp[0], r1 = lp[1];
            const unsigned tk[8] = {r0.x, r0.y, r0.z, r0.w,
                                    r1.x, r1.y, r1.z, r1.w};
#pragma unroll
            for (int k = 0; k < 8; ++k) {
                unsigned ky = tk[k];
                if (ky < md[KNN - 1]) {    // sentinel skip
#pragma unroll
                    for (int i = 0; i < KNN; ++i) {
                        const unsigned mn = min(ky, md[i]);
                        const unsigned mx = max(ky, md[i]);
                        md[i] = mn; ky = mx;
                    }
                }
            }
        }
#pragma unroll
        for (int k = 0; k < KNN; ++k) {
            const unsigned ky = md[k];
            int nb;
            if (ky >= SENT) {
                nb = qi;  // unfilled -> self (contributes 0, matches ref)
            } else {
                const int sp = (int)(ky & 0x1FFFu);
                const float4 cc = csb[sp];
                const float dx = cc.x - qx;
                const float dy = cc.y - qy;
                const float dz = cc.z - qz;
                const float d2 = fmaf(dx, dx, fmaf(dy, dy, dz * dz));
                // reference: idx = where(sqrt(d2) > 0.1, self_idx, idx)
                nb = (sqrtf(d2) > 0.1f) ? qi : sidx[b * NPTS + sp];
            }
            fidx[q * KNN + k] = nb;
        }
    }
    __syncthreads();

    // loss gather: 512 threads <-> 64 q x 8 nn, full 16-ch rows
    const int q2 = t >> 3;
    const int j2 = t & 7;
    const int qg = qid[q2];
    const int nb = fidx[q2 * KNN + j2];
    const float* mrow = mask + ((size_t)b * NPTS + qg) * KS;
    const float* nrow = mask + ((size_t)b * NPTS + nb) * KS;
    float acc = 0.0f;
#pragma unroll
    for (int c = 0; c < KS; c += 4) {
        const float4 a = *(const float4*)(mrow + c);
        const float4 v = *(const float4*)(nrow + c);
        acc += fabsf(a.x - v.x) + fabsf(a.y - v.y) +
               fabsf(a.z - v.z) + fabsf(a.w - v.w);
    }

    // block reduction: wave shuffle -> LDS -> one atomic per block
#pragma unroll
    for (int off = 32; off > 0; off >>= 1) acc += __shfl_down(acc, off);
    if ((t & 63) == 0) red[s] = acc;
    __syncthreads();
    if (t == 0) {
        float sum = 0.0f;
#pragma unroll
        for (int i = 0; i < NWAVE; ++i) sum += red[i];
        atomicAdd(out, sum * (1.0f / (BATCH * NPTS * KNN)));
    }
}

extern "C" void kernel_launch(void* const* d_in, const int* in_sizes, int n_in,
                              void* d_out, int out_size, void* d_ws, size_t ws_size,
                              hipStream_t stream) {
    const float* pc   = (const float*)d_in[0];  // (2, 8192, 3)
    const float* mask = (const float*)d_in[1];  // (2, 8192, 16)
    float* out = (float*)d_out;                 // scalar, poisoned 0xAA each call

    // workspace layout (336 KB used)
    float4* cs     = (float4*)d_ws;                              // 256 KB
    int*    sidx   = (int*)((char*)d_ws + 262144);               //  64 KB
    int*    cstart = (int*)((char*)d_ws + 327680);               //   8 KB

    hipLaunchKernelGGL(build_kernel, dim3(16), dim3(1024), 0, stream,
                       pc, cs, sidx, cstart, out);
    hipLaunchKernelGGL(knn_loss_kernel, dim3(NBLK), dim3(512), 0, stream,
                       cs, sidx, cstart, mask, out);
}